// Round 10
// baseline (350.370 us; speedup 1.0000x reference)
//
#include <hip/hip_runtime.h>
#include <hip/hip_bf16.h>

#define T_TOK 2048
#define HID 2048
#define IMED 768
#define NEXP 16
#define TOPK 8
#define MAXPAIR (T_TOK * TOPK)

using f32x4  = __attribute__((ext_vector_type(4))) float;
using bf16x8 = __attribute__((ext_vector_type(8))) __bf16;

__device__ __forceinline__ f32x4 mfma16(bf16x8 a, bf16x8 b, f32x4 c) {
  return __builtin_amdgcn_mfma_f32_16x16x32_bf16(a, b, c, 0, 0, 0);
}

__device__ __forceinline__ void gload16(const void* g, void* lds) {
  __builtin_amdgcn_global_load_lds((const __attribute__((address_space(1))) unsigned int*)g,
                                   (__attribute__((address_space(3))) unsigned int*)lds,
                                   16, 0, 0);
}

// ---------- prep: fp32 -> bf16 copy of hidden_states ----------
__global__ void moe_cvt_x(const float* __restrict__ X, __bf16* __restrict__ XB) {
  int i = (blockIdx.x * blockDim.x + threadIdx.x) * 8;
  float4 v0 = *(const float4*)&X[i];
  float4 v1 = *(const float4*)&X[i + 4];
  bf16x8 o;
  o[0] = (__bf16)v0.x; o[1] = (__bf16)v0.y; o[2] = (__bf16)v0.z; o[3] = (__bf16)v0.w;
  o[4] = (__bf16)v1.x; o[5] = (__bf16)v1.y; o[6] = (__bf16)v1.z; o[7] = (__bf16)v1.w;
  *(bf16x8*)&XB[i] = o;
}

// ---------- prep v2: per-expert transpose [R][C] f32 -> [C][R] bf16 ----------
// 256r x 64c input tiles -> output 64 rows x 256 cols (512B contiguous writes).
// LDS stored pre-transposed [c=64][r=257 f32]: write banks = (4k+i+r)%32 (2-way,
// free); read = contiguous b128.
__global__ __launch_bounds__(512) void moe_transpose(const float* __restrict__ in,
                                                     __bf16* __restrict__ out,
                                                     int R, int C) {
  __shared__ __align__(16) float tile[64][257];
  const int e = blockIdx.z;
  const float* ib = in + (size_t)e * R * C;
  __bf16* ob = out + (size_t)e * R * C;
  const int c0 = blockIdx.x * 64, r0 = blockIdx.y * 256;
  const int tid = threadIdx.x;
  // read pass: 8 iters x 32 rows; store transposed into LDS
  const int lc = (tid & 15) * 4;
  const int rr = tid >> 4;             // 0..31
#pragma unroll
  for (int it = 0; it < 8; ++it) {
    const int r = it * 32 + rr;
    float4 v = *(const float4*)&ib[(size_t)(r0 + r) * C + c0 + lc];
    tile[lc + 0][r] = v.x; tile[lc + 1][r] = v.y;
    tile[lc + 2][r] = v.z; tile[lc + 3][r] = v.w;
  }
  __syncthreads();
  // write pass: 4 iters x 16 out-rows; 32 lanes cover 512B contiguous per row
  const int ch = tid & 31;             // 8-f32 chunk
  const int ocb = tid >> 5;            // 0..15
#pragma unroll
  for (int it = 0; it < 4; ++it) {
    const int oc = it * 16 + ocb;
    f32x4 a = *(const f32x4*)&tile[oc][ch * 8];
    f32x4 b = *(const f32x4*)&tile[oc][ch * 8 + 4];
    bf16x8 o;
    o[0] = (__bf16)a[0]; o[1] = (__bf16)a[1]; o[2] = (__bf16)a[2]; o[3] = (__bf16)a[3];
    o[4] = (__bf16)b[0]; o[5] = (__bf16)b[1]; o[6] = (__bf16)b[2]; o[7] = (__bf16)b[3];
    *(bf16x8*)&ob[(size_t)(c0 + oc) * R + r0 + ch * 8] = o;
  }
}

// ---------- fused routing: counts + offsets + block-prefix + scatter ----------
// meta ints: [0..15]=counts  [16..32]=pair offsets(17)  [49..65]=128-blk prefix(17)
__global__ __launch_bounds__(1024) void moe_route(const int* __restrict__ idx,
                                                  const float* __restrict__ wgt,
                                                  int* __restrict__ meta,
                                                  int* __restrict__ rtok,
                                                  float* __restrict__ rw,
                                                  int* __restrict__ ptok,
                                                  int* __restrict__ pcnt) {
  __shared__ int cntS[NEXP];
  __shared__ int curS[NEXP];
  const int tid = threadIdx.x;
  if (tid < NEXP) cntS[tid] = 0;
  __syncthreads();

  const int t0 = tid, t1 = tid + 1024;
  float c0[NEXP], c1[NEXP];
#pragma unroll
  for (int e = 0; e < NEXP; ++e) { c0[e] = 0.f; c1[e] = 0.f; }
  for (int k = 0; k < TOPK; ++k) {
    c0[idx[t0 * TOPK + k]] += wgt[t0 * TOPK + k];
    c1[idx[t1 * TOPK + k]] += wgt[t1 * TOPK + k];
  }
  int n0 = 0, n1 = 0;
#pragma unroll
  for (int e = 0; e < NEXP; ++e) {
    if (c0[e] != 0.f) { atomicAdd(&cntS[e], 1); ++n0; }
    if (c1[e] != 0.f) { atomicAdd(&cntS[e], 1); ++n1; }
  }
  pcnt[t0] = n0; pcnt[t1] = n1;
  __syncthreads();

  if (tid == 0) {
    int s = 0, b = 0;
    for (int e = 0; e < NEXP; ++e) {
      meta[e] = cntS[e];
      meta[16 + e] = s;
      meta[49 + e] = b;
      curS[e] = s;
      s += cntS[e];
      b += (cntS[e] + 127) >> 7;
    }
    meta[32] = s;
    meta[65] = b;
  }
  __syncthreads();

  int s0 = 0, s1 = 0;
#pragma unroll
  for (int e = 0; e < NEXP; ++e) {
    if (c0[e] != 0.f) {
      int p = atomicAdd(&curS[e], 1);
      rtok[p] = t0; rw[p] = c0[e];
      ptok[t0 * TOPK + s0] = p; ++s0;
    }
    if (c1[e] != 0.f) {
      int p = atomicAdd(&curS[e], 1);
      rtok[p] = t1; rw[p] = c1[e];
      ptok[t1 * TOPK + s1] = p; ++s1;
    }
  }
}

// ---------- GEMM1: 128 pairs x (64 gate + 64 up cols), K=2048 ----------
// m97 structure. Work-queue, bi-outer / ny-inner: 12 consecutive wgids share one
// m-block (A-tile L2 reuse) and mostly one expert (B-panel L2 reuse).
__global__ __launch_bounds__(256) void moe_gemm1(
    const __bf16* __restrict__ XB, const __bf16* __restrict__ WguT,
    const int* __restrict__ rtok, const float* __restrict__ rw,
    const int* __restrict__ meta, __bf16* __restrict__ ACT) {
  const int orig = blockIdx.x;               // 1728 = 8 XCDs x 216 (bijective)
  const int wgid = (orig & 7) * 216 + (orig >> 3);
  const int bi = wgid / 12;
  const int ny = wgid % 12;
  if (bi >= meta[65]) return;
  int e = 0;
#pragma unroll
  for (int k = 1; k < NEXP; ++k) if (meta[49 + k] <= bi) e = k;
  const int mx = bi - meta[49 + e];

  const int seg0 = meta[16 + e];
  const int cnt  = meta[16 + e + 1] - seg0;
  const int m0 = mx * 128;
  const int n0 = ny * 64;

  __shared__ char As[16384];   // 128 rows x 128B, linear; src pre-swizzled
  __shared__ char Bs[16384];

  const int tid = threadIdx.x;
  const int l = tid & 63;
  const int w = tid >> 6;
  const int wm = w >> 1, wn = w & 1;
  const int swoff = 16 * ((l & 7) ^ (l >> 3));

  const char* baseA[4];
  const char* baseB[4];
#pragma unroll
  for (int q = 0; q < 4; ++q) {
    const int r = (w * 4 + q) * 8 + (l >> 3);
    int grow = m0 + r; if (grow >= cnt) grow = cnt - 1;
    const int tok = rtok[seg0 + grow];
    baseA[q] = (const char*)(XB + (size_t)tok * HID) + swoff;
    const int sec = r >> 6, s = r & 63;
    const int wrow = (s < 32) ? (n0 + sec * 32 + s) : (IMED + n0 + sec * 32 + (s - 32));
    baseB[q] = (const char*)(WguT + ((size_t)e * (2 * IMED) + wrow) * HID) + swoff;
  }

  f32x4 acc[4][4];   // ni 0,1 = gate ; 2,3 = up
  const f32x4 zero = {0.f, 0.f, 0.f, 0.f};
#pragma unroll
  for (int i = 0; i < 4; ++i)
#pragma unroll
    for (int j = 0; j < 4; ++j) acc[i][j] = zero;

  for (int k0b = 0; k0b < HID * 2; k0b += 128) {
#pragma unroll
    for (int q = 0; q < 4; ++q) {
      gload16(baseA[q] + k0b, &As[(w * 4 + q) * 1024]);
      gload16(baseB[q] + k0b, &Bs[(w * 4 + q) * 1024]);
    }
    __syncthreads();
#pragma unroll
    for (int ks = 0; ks < 2; ++ks) {
      const int colb = ks * 64 + (l >> 4) * 16;
      bf16x8 af[4], bf[4];
#pragma unroll
      for (int mi = 0; mi < 4; ++mi) {
        const int row = wm * 64 + mi * 16 + (l & 15);
        af[mi] = *(const bf16x8*)&As[row * 128 + (colb ^ ((row & 7) << 4))];
      }
#pragma unroll
      for (int ni = 0; ni < 4; ++ni) {
        const int row = wn * 64 + ni * 16 + (l & 15);
        bf[ni] = *(const bf16x8*)&Bs[row * 128 + (colb ^ ((row & 7) << 4))];
      }
#pragma unroll
      for (int mi = 0; mi < 4; ++mi)
#pragma unroll
        for (int ni = 0; ni < 4; ++ni)
          acc[mi][ni] = mfma16(af[mi], bf[ni], acc[mi][ni]);
    }
    __syncthreads();
  }

  const int cbase = n0 + wn * 32;
#pragma unroll
  for (int mi = 0; mi < 4; ++mi) {
    const int rb = wm * 64 + mi * 16 + ((l >> 4) << 2);
#pragma unroll
    for (int r = 0; r < 4; ++r) {
      const int row = m0 + rb + r;
      if (row < cnt) {
        const float wgt = rw[seg0 + row];
#pragma unroll
        for (int ni = 0; ni < 2; ++ni) {
          const float g = acc[mi][ni][r];
          const float u = acc[mi][ni + 2][r];
          const float s = g / (1.f + __expf(-g));
          ACT[(size_t)(seg0 + row) * IMED + cbase + ni * 16 + (l & 15)] = (__bf16)(s * u * wgt);
        }
      }
    }
  }
}

// ---------- GEMM2: 128 pairs x 128 H-cols, K=768, single-buffer, bf16 store ----------
__global__ __launch_bounds__(256) void moe_gemm2(
    const __bf16* __restrict__ ACT, const __bf16* __restrict__ WdT,
    const int* __restrict__ meta, __bf16* __restrict__ ACT2) {
  const int orig = blockIdx.x;               // 2304 = 8 XCDs x 288 (bijective)
  const int wgid = (orig & 7) * 288 + (orig >> 3);
  const int bi = wgid / 16;                  // bi-outer: A-tile reused by 16 ny
  const int ny = wgid % 16;
  if (bi >= meta[65]) return;
  int e = 0;
#pragma unroll
  for (int k = 1; k < NEXP; ++k) if (meta[49 + k] <= bi) e = k;
  const int mx = bi - meta[49 + e];

  const int seg0 = meta[16 + e];
  const int cnt  = meta[16 + e + 1] - seg0;
  const int m0 = mx * 128;
  const int n0 = ny * 128;

  __shared__ char As[16384];
  __shared__ char Bs[16384];

  const int tid = threadIdx.x;
  const int l = tid & 63;
  const int w = tid >> 6;
  const int wm = w >> 1, wn = w & 1;
  const int swoff = 16 * ((l & 7) ^ (l >> 3));

  const char* baseA[4];
  const char* baseB[4];
#pragma unroll
  for (int q = 0; q < 4; ++q) {
    const int r = (w * 4 + q) * 8 + (l >> 3);
    int grow = m0 + r; if (grow >= cnt) grow = cnt - 1;
    baseA[q] = (const char*)(ACT + (size_t)(seg0 + grow) * IMED) + swoff;
    baseB[q] = (const char*)(WdT + ((size_t)e * HID + n0 + r) * IMED) + swoff;
  }

  f32x4 acc[4][4];
  const f32x4 zero = {0.f, 0.f, 0.f, 0.f};
#pragma unroll
  for (int i = 0; i < 4; ++i)
#pragma unroll
    for (int j = 0; j < 4; ++j) acc[i][j] = zero;

  for (int k0b = 0; k0b < IMED * 2; k0b += 128) {
#pragma unroll
    for (int q = 0; q < 4; ++q) {
      gload16(baseA[q] + k0b, &As[(w * 4 + q) * 1024]);
      gload16(baseB[q] + k0b, &Bs[(w * 4 + q) * 1024]);
    }
    __syncthreads();
#pragma unroll
    for (int ks = 0; ks < 2; ++ks) {
      const int colb = ks * 64 + (l >> 4) * 16;
      bf16x8 af[4], bf[4];
#pragma unroll
      for (int mi = 0; mi < 4; ++mi) {
        const int row = wm * 64 + mi * 16 + (l & 15);
        af[mi] = *(const bf16x8*)&As[row * 128 + (colb ^ ((row & 7) << 4))];
      }
#pragma unroll
      for (int ni = 0; ni < 4; ++ni) {
        const int row = wn * 64 + ni * 16 + (l & 15);
        bf[ni] = *(const bf16x8*)&Bs[row * 128 + (colb ^ ((row & 7) << 4))];
      }
#pragma unroll
      for (int mi = 0; mi < 4; ++mi)
#pragma unroll
        for (int ni = 0; ni < 4; ++ni)
          acc[mi][ni] = mfma16(af[mi], bf[ni], acc[mi][ni]);
    }
    __syncthreads();
  }

#pragma unroll
  for (int mi = 0; mi < 4; ++mi) {
    const int rb = wm * 64 + mi * 16 + ((l >> 4) << 2);
#pragma unroll
    for (int r = 0; r < 4; ++r) {
      const int row = m0 + rb + r;
      if (row < cnt) {
#pragma unroll
        for (int ni = 0; ni < 4; ++ni)
          ACT2[(size_t)(seg0 + row) * HID + n0 + wn * 64 + ni * 16 + (l & 15)] =
              (__bf16)acc[mi][ni][r];
      }
    }
  }
}

// ---------- combine: out[t][h] = sum_k ACT2[ptok[t][k]][h] ----------
__global__ __launch_bounds__(256) void moe_combine(const __bf16* __restrict__ ACT2,
                                                   const int* __restrict__ ptok,
                                                   const int* __restrict__ pcnt,
                                                   float* __restrict__ out) {
  const int t = blockIdx.x;
  const int h = threadIdx.x * 8;
  const int n = pcnt[t];
  float a[8];
#pragma unroll
  for (int j = 0; j < 8; ++j) a[j] = 0.f;
  for (int k = 0; k < n; ++k) {
    const int p = ptok[t * TOPK + k];
    bf16x8 v = *(const bf16x8*)&ACT2[(size_t)p * HID + h];
#pragma unroll
    for (int j = 0; j < 8; ++j) a[j] += (float)v[j];
  }
  float4 o0 = {a[0], a[1], a[2], a[3]};
  float4 o1 = {a[4], a[5], a[6], a[7]};
  *(float4*)&out[(size_t)t * HID + h] = o0;
  *(float4*)&out[(size_t)t * HID + h + 4] = o1;
}

extern "C" void kernel_launch(void* const* d_in, const int* in_sizes, int n_in,
                              void* d_out, int out_size, void* d_ws, size_t ws_size,
                              hipStream_t stream) {
  const float* X   = (const float*)d_in[0];
  const float* GUP = (const float*)d_in[1];
  const float* DP  = (const float*)d_in[2];
  const int*   IDX = (const int*)d_in[3];
  const float* W   = (const float*)d_in[4];
  float* out = (float*)d_out;

  size_t off = 0;
  auto alloc = [&](size_t bytes) -> void* {
    void* p = (char*)d_ws + off;
    off = (off + bytes + 255) & ~(size_t)255;
    return p;
  };
  __bf16* XB      = (__bf16*)alloc((size_t)T_TOK * HID * 2);
  __bf16* WguT    = (__bf16*)alloc((size_t)NEXP * 2 * IMED * HID * 2);
  __bf16* WdT     = (__bf16*)alloc((size_t)NEXP * HID * IMED * 2);
  __bf16* ACT     = (__bf16*)alloc((size_t)(MAXPAIR + 128) * IMED * 2);
  int*    meta    = (int*)alloc(128 * 4);
  int*    rtok    = (int*)alloc((size_t)MAXPAIR * 4);
  float*  rw      = (float*)alloc((size_t)MAXPAIR * 4);
  int*    ptok    = (int*)alloc((size_t)T_TOK * TOPK * 4);
  int*    pcnt    = (int*)alloc((size_t)T_TOK * 4);
  if (off > ws_size) return;

  // ACT2 aliases WguT: GEMM1 (last reader of WguT) completes before GEMM2
  // (first writer of ACT2) on the same stream.
  __bf16* ACT2 = WguT;

  moe_cvt_x<<<T_TOK * HID / (256 * 8), 256, 0, stream>>>(X, XB);
  moe_transpose<<<dim3((2 * IMED) / 64, HID / 256, NEXP), 512, 0, stream>>>(GUP, WguT, HID, 2 * IMED);
  moe_transpose<<<dim3(HID / 64, IMED / 256, NEXP), 512, 0, stream>>>(DP, WdT, IMED, HID);
  moe_route<<<1, 1024, 0, stream>>>(IDX, W, meta, rtok, rw, ptok, pcnt);
  moe_gemm1<<<1728, 256, 0, stream>>>(XB, WguT, rtok, rw, meta, ACT);
  moe_gemm2<<<2304, 256, 0, stream>>>(ACT, WdT, meta, ACT2);
  moe_combine<<<T_TOK, 256, 0, stream>>>(ACT2, ptok, pcnt, out);
}

// Round 11
// 318.136 us; speedup vs baseline: 1.1013x; 1.1013x over previous
//
#include <hip/hip_runtime.h>
#include <hip/hip_bf16.h>

#define T_TOK 2048
#define HID 2048
#define IMED 768
#define NEXP 16
#define TOPK 8
#define MAXPAIR (T_TOK * TOPK)

using f32x4  = __attribute__((ext_vector_type(4))) float;
using bf16x8 = __attribute__((ext_vector_type(8))) __bf16;

__device__ __forceinline__ f32x4 mfma16(bf16x8 a, bf16x8 b, f32x4 c) {
  return __builtin_amdgcn_mfma_f32_16x16x32_bf16(a, b, c, 0, 0, 0);
}

__device__ __forceinline__ void gload16(const void* g, void* lds) {
  __builtin_amdgcn_global_load_lds((const __attribute__((address_space(1))) unsigned int*)g,
                                   (__attribute__((address_space(3))) unsigned int*)lds,
                                   16, 0, 0);
}

// ---------- prep: fp32 -> bf16 copy of hidden_states ----------
__global__ void moe_cvt_x(const float* __restrict__ X, __bf16* __restrict__ XB) {
  int i = (blockIdx.x * blockDim.x + threadIdx.x) * 8;
  float4 v0 = *(const float4*)&X[i];
  float4 v1 = *(const float4*)&X[i + 4];
  bf16x8 o;
  o[0] = (__bf16)v0.x; o[1] = (__bf16)v0.y; o[2] = (__bf16)v0.z; o[3] = (__bf16)v0.w;
  o[4] = (__bf16)v1.x; o[5] = (__bf16)v1.y; o[6] = (__bf16)v1.z; o[7] = (__bf16)v1.w;
  *(bf16x8*)&XB[i] = o;
}

// ---------- prep v2: per-expert transpose [R][C] f32 -> [C][R] bf16 ----------
// 256r x 64c input tiles -> output 64 rows x 512B contiguous writes.
__global__ __launch_bounds__(512) void moe_transpose(const float* __restrict__ in,
                                                     __bf16* __restrict__ out,
                                                     int R, int C) {
  __shared__ __align__(16) float tile[64][257];
  const int e = blockIdx.z;
  const float* ib = in + (size_t)e * R * C;
  __bf16* ob = out + (size_t)e * R * C;
  const int c0 = blockIdx.x * 64, r0 = blockIdx.y * 256;
  const int tid = threadIdx.x;
  const int lc = (tid & 15) * 4;
  const int rr = tid >> 4;             // 0..31
#pragma unroll
  for (int it = 0; it < 8; ++it) {
    const int r = it * 32 + rr;
    float4 v = *(const float4*)&ib[(size_t)(r0 + r) * C + c0 + lc];
    tile[lc + 0][r] = v.x; tile[lc + 1][r] = v.y;
    tile[lc + 2][r] = v.z; tile[lc + 3][r] = v.w;
  }
  __syncthreads();
  const int ch = tid & 31;
  const int ocb = tid >> 5;            // 0..15
#pragma unroll
  for (int it = 0; it < 4; ++it) {
    const int oc = it * 16 + ocb;
    f32x4 a = *(const f32x4*)&tile[oc][ch * 8];
    f32x4 b = *(const f32x4*)&tile[oc][ch * 8 + 4];
    bf16x8 o;
    o[0] = (__bf16)a[0]; o[1] = (__bf16)a[1]; o[2] = (__bf16)a[2]; o[3] = (__bf16)a[3];
    o[4] = (__bf16)b[0]; o[5] = (__bf16)b[1]; o[6] = (__bf16)b[2]; o[7] = (__bf16)b[3];
    *(bf16x8*)&ob[(size_t)(c0 + oc) * R + r0 + ch * 8] = o;
  }
}

// ---------- fused routing ----------
// meta ints: [0..15]=counts  [16..32]=pair offsets(17)
__global__ __launch_bounds__(1024) void moe_route(const int* __restrict__ idx,
                                                  const float* __restrict__ wgt,
                                                  int* __restrict__ meta,
                                                  int* __restrict__ rtok,
                                                  float* __restrict__ rw,
                                                  int* __restrict__ ptok,
                                                  int* __restrict__ pcnt) {
  __shared__ int cntS[NEXP];
  __shared__ int curS[NEXP];
  const int tid = threadIdx.x;
  if (tid < NEXP) cntS[tid] = 0;
  __syncthreads();

  const int t0 = tid, t1 = tid + 1024;
  float c0[NEXP], c1[NEXP];
#pragma unroll
  for (int e = 0; e < NEXP; ++e) { c0[e] = 0.f; c1[e] = 0.f; }
  for (int k = 0; k < TOPK; ++k) {
    c0[idx[t0 * TOPK + k]] += wgt[t0 * TOPK + k];
    c1[idx[t1 * TOPK + k]] += wgt[t1 * TOPK + k];
  }
  int n0 = 0, n1 = 0;
#pragma unroll
  for (int e = 0; e < NEXP; ++e) {
    if (c0[e] != 0.f) { atomicAdd(&cntS[e], 1); ++n0; }
    if (c1[e] != 0.f) { atomicAdd(&cntS[e], 1); ++n1; }
  }
  pcnt[t0] = n0; pcnt[t1] = n1;
  __syncthreads();

  if (tid == 0) {
    int s = 0;
    for (int e = 0; e < NEXP; ++e) {
      meta[e] = cntS[e];
      meta[16 + e] = s;
      curS[e] = s;
      s += cntS[e];
    }
    meta[32] = s;
  }
  __syncthreads();

  int s0 = 0, s1 = 0;
#pragma unroll
  for (int e = 0; e < NEXP; ++e) {
    if (c0[e] != 0.f) {
      int p = atomicAdd(&curS[e], 1);
      rtok[p] = t0; rw[p] = c0[e];
      ptok[t0 * TOPK + s0] = p; ++s0;
    }
    if (c1[e] != 0.f) {
      int p = atomicAdd(&curS[e], 1);
      rtok[p] = t1; rw[p] = c1[e];
      ptok[t1 * TOPK + s1] = p; ++s1;
    }
  }
}

// ---------- GEMM1: 128 pairs x (64 gate + 64 up cols), K=2048 ----------
// m97 structure; R7 grid mapping (mx fastest, e outer) -> FETCH ~97MB.
__global__ __launch_bounds__(256) void moe_gemm1(
    const __bf16* __restrict__ XB, const __bf16* __restrict__ WguT,
    const int* __restrict__ rtok, const float* __restrict__ rw,
    const int* __restrict__ meta, __bf16* __restrict__ ACT) {
  const int orig = blockIdx.x;               // 3072 = 8 XCDs x 384 (bijective)
  const int wgid = (orig & 7) * 384 + (orig >> 3);
  const int mx = wgid & 15;
  const int ny = (wgid >> 4) % 12;
  const int e  = wgid / 192;

  const int seg0 = meta[16 + e];
  const int cnt  = meta[16 + e + 1] - seg0;
  const int m0 = mx * 128;
  if (m0 >= cnt) return;
  const int n0 = ny * 64;

  __shared__ char As[16384];   // 128 rows x 128B, linear; src pre-swizzled
  __shared__ char Bs[16384];

  const int tid = threadIdx.x;
  const int l = tid & 63;
  const int w = tid >> 6;
  const int wm = w >> 1, wn = w & 1;
  const int swoff = 16 * ((l & 7) ^ (l >> 3));

  const char* baseA[4];
  const char* baseB[4];
#pragma unroll
  for (int q = 0; q < 4; ++q) {
    const int r = (w * 4 + q) * 8 + (l >> 3);
    int grow = m0 + r; if (grow >= cnt) grow = cnt - 1;
    const int tok = rtok[seg0 + grow];
    baseA[q] = (const char*)(XB + (size_t)tok * HID) + swoff;
    const int sec = r >> 6, s = r & 63;
    const int wrow = (s < 32) ? (n0 + sec * 32 + s) : (IMED + n0 + sec * 32 + (s - 32));
    baseB[q] = (const char*)(WguT + ((size_t)e * (2 * IMED) + wrow) * HID) + swoff;
  }

  f32x4 acc[4][4];   // ni 0,1 = gate ; 2,3 = up
  const f32x4 zero = {0.f, 0.f, 0.f, 0.f};
#pragma unroll
  for (int i = 0; i < 4; ++i)
#pragma unroll
    for (int j = 0; j < 4; ++j) acc[i][j] = zero;

  for (int k0b = 0; k0b < HID * 2; k0b += 128) {
#pragma unroll
    for (int q = 0; q < 4; ++q) {
      gload16(baseA[q] + k0b, &As[(w * 4 + q) * 1024]);
      gload16(baseB[q] + k0b, &Bs[(w * 4 + q) * 1024]);
    }
    __syncthreads();
#pragma unroll
    for (int ks = 0; ks < 2; ++ks) {
      const int colb = ks * 64 + (l >> 4) * 16;
      bf16x8 af[4], bf[4];
#pragma unroll
      for (int mi = 0; mi < 4; ++mi) {
        const int row = wm * 64 + mi * 16 + (l & 15);
        af[mi] = *(const bf16x8*)&As[row * 128 + (colb ^ ((row & 7) << 4))];
      }
#pragma unroll
      for (int ni = 0; ni < 4; ++ni) {
        const int row = wn * 64 + ni * 16 + (l & 15);
        bf[ni] = *(const bf16x8*)&Bs[row * 128 + (colb ^ ((row & 7) << 4))];
      }
#pragma unroll
      for (int mi = 0; mi < 4; ++mi)
#pragma unroll
        for (int ni = 0; ni < 4; ++ni)
          acc[mi][ni] = mfma16(af[mi], bf[ni], acc[mi][ni]);
    }
    __syncthreads();
  }

  const int cbase = n0 + wn * 32;
#pragma unroll
  for (int mi = 0; mi < 4; ++mi) {
    const int rb = wm * 64 + mi * 16 + ((l >> 4) << 2);
#pragma unroll
    for (int r = 0; r < 4; ++r) {
      const int row = m0 + rb + r;
      if (row < cnt) {
        const float wgt = rw[seg0 + row];
#pragma unroll
        for (int ni = 0; ni < 2; ++ni) {
          const float g = acc[mi][ni][r];
          const float u = acc[mi][ni + 2][r];
          const float s = g / (1.f + __expf(-g));
          ACT[(size_t)(seg0 + row) * IMED + cbase + ni * 16 + (l & 15)] = (__bf16)(s * u * wgt);
        }
      }
    }
  }
}

// ---------- GEMM2: 128 pairs x 128 H-cols, K=768, single-buffer, bf16 store ----------
__global__ __launch_bounds__(256) void moe_gemm2(
    const __bf16* __restrict__ ACT, const __bf16* __restrict__ WdT,
    const int* __restrict__ meta, __bf16* __restrict__ ACT2) {
  const int orig = blockIdx.x;               // 4096 = 8 x 512 (bijective)
  const int wgid = (orig & 7) * 512 + (orig >> 3);
  const int mx = wgid & 15;
  const int ny = (wgid >> 4) & 15;
  const int e  = wgid >> 8;

  const int seg0 = meta[16 + e];
  const int cnt  = meta[16 + e + 1] - seg0;
  const int m0 = mx * 128;
  if (m0 >= cnt) return;
  const int n0 = ny * 128;

  __shared__ char As[16384];
  __shared__ char Bs[16384];

  const int tid = threadIdx.x;
  const int l = tid & 63;
  const int w = tid >> 6;
  const int wm = w >> 1, wn = w & 1;
  const int swoff = 16 * ((l & 7) ^ (l >> 3));

  const char* baseA[4];
  const char* baseB[4];
#pragma unroll
  for (int q = 0; q < 4; ++q) {
    const int r = (w * 4 + q) * 8 + (l >> 3);
    int grow = m0 + r; if (grow >= cnt) grow = cnt - 1;
    baseA[q] = (const char*)(ACT + (size_t)(seg0 + grow) * IMED) + swoff;
    baseB[q] = (const char*)(WdT + ((size_t)e * HID + n0 + r) * IMED) + swoff;
  }

  f32x4 acc[4][4];
  const f32x4 zero = {0.f, 0.f, 0.f, 0.f};
#pragma unroll
  for (int i = 0; i < 4; ++i)
#pragma unroll
    for (int j = 0; j < 4; ++j) acc[i][j] = zero;

  for (int k0b = 0; k0b < IMED * 2; k0b += 128) {
#pragma unroll
    for (int q = 0; q < 4; ++q) {
      gload16(baseA[q] + k0b, &As[(w * 4 + q) * 1024]);
      gload16(baseB[q] + k0b, &Bs[(w * 4 + q) * 1024]);
    }
    __syncthreads();
#pragma unroll
    for (int ks = 0; ks < 2; ++ks) {
      const int colb = ks * 64 + (l >> 4) * 16;
      bf16x8 af[4], bf[4];
#pragma unroll
      for (int mi = 0; mi < 4; ++mi) {
        const int row = wm * 64 + mi * 16 + (l & 15);
        af[mi] = *(const bf16x8*)&As[row * 128 + (colb ^ ((row & 7) << 4))];
      }
#pragma unroll
      for (int ni = 0; ni < 4; ++ni) {
        const int row = wn * 64 + ni * 16 + (l & 15);
        bf[ni] = *(const bf16x8*)&Bs[row * 128 + (colb ^ ((row & 7) << 4))];
      }
#pragma unroll
      for (int mi = 0; mi < 4; ++mi)
#pragma unroll
        for (int ni = 0; ni < 4; ++ni)
          acc[mi][ni] = mfma16(af[mi], bf[ni], acc[mi][ni]);
    }
    __syncthreads();
  }

#pragma unroll
  for (int mi = 0; mi < 4; ++mi) {
    const int rb = wm * 64 + mi * 16 + ((l >> 4) << 2);
#pragma unroll
    for (int r = 0; r < 4; ++r) {
      const int row = m0 + rb + r;
      if (row < cnt) {
#pragma unroll
        for (int ni = 0; ni < 4; ++ni)
          ACT2[(size_t)(seg0 + row) * HID + n0 + wn * 64 + ni * 16 + (l & 15)] =
              (__bf16)acc[mi][ni][r];
      }
    }
  }
}

// ---------- combine: out[t][h] = sum_k ACT2[ptok[t][k]][h] ----------
__global__ __launch_bounds__(256) void moe_combine(const __bf16* __restrict__ ACT2,
                                                   const int* __restrict__ ptok,
                                                   const int* __restrict__ pcnt,
                                                   float* __restrict__ out) {
  const int t = blockIdx.x;
  const int h = threadIdx.x * 8;
  const int n = pcnt[t];
  float a[8];
#pragma unroll
  for (int j = 0; j < 8; ++j) a[j] = 0.f;
  for (int k = 0; k < n; ++k) {
    const int p = ptok[t * TOPK + k];
    bf16x8 v = *(const bf16x8*)&ACT2[(size_t)p * HID + h];
#pragma unroll
    for (int j = 0; j < 8; ++j) a[j] += (float)v[j];
  }
  float4 o0 = {a[0], a[1], a[2], a[3]};
  float4 o1 = {a[4], a[5], a[6], a[7]};
  *(float4*)&out[(size_t)t * HID + h] = o0;
  *(float4*)&out[(size_t)t * HID + h + 4] = o1;
}

extern "C" void kernel_launch(void* const* d_in, const int* in_sizes, int n_in,
                              void* d_out, int out_size, void* d_ws, size_t ws_size,
                              hipStream_t stream) {
  const float* X   = (const float*)d_in[0];
  const float* GUP = (const float*)d_in[1];
  const float* DP  = (const float*)d_in[2];
  const int*   IDX = (const int*)d_in[3];
  const float* W   = (const float*)d_in[4];
  float* out = (float*)d_out;

  size_t off = 0;
  auto alloc = [&](size_t bytes) -> void* {
    void* p = (char*)d_ws + off;
    off = (off + bytes + 255) & ~(size_t)255;
    return p;
  };
  __bf16* XB      = (__bf16*)alloc((size_t)T_TOK * HID * 2);
  __bf16* WguT    = (__bf16*)alloc((size_t)NEXP * 2 * IMED * HID * 2);
  __bf16* WdT     = (__bf16*)alloc((size_t)NEXP * HID * IMED * 2);
  __bf16* ACT     = (__bf16*)alloc((size_t)(MAXPAIR + 128) * IMED * 2);
  int*    meta    = (int*)alloc(128 * 4);
  int*    rtok    = (int*)alloc((size_t)MAXPAIR * 4);
  float*  rw      = (float*)alloc((size_t)MAXPAIR * 4);
  int*    ptok    = (int*)alloc((size_t)T_TOK * TOPK * 4);
  int*    pcnt    = (int*)alloc((size_t)T_TOK * 4);
  if (off > ws_size) return;

  // ACT2 aliases WguT: GEMM1 (last reader of WguT) completes before GEMM2
  // (first writer of ACT2) on the same stream.
  __bf16* ACT2 = WguT;

  moe_cvt_x<<<T_TOK * HID / (256 * 8), 256, 0, stream>>>(X, XB);
  moe_transpose<<<dim3((2 * IMED) / 64, HID / 256, NEXP), 512, 0, stream>>>(GUP, WguT, HID, 2 * IMED);
  moe_transpose<<<dim3(HID / 64, IMED / 256, NEXP), 512, 0, stream>>>(DP, WdT, IMED, HID);
  moe_route<<<1, 1024, 0, stream>>>(IDX, W, meta, rtok, rw, ptok, pcnt);
  moe_gemm1<<<3072, 256, 0, stream>>>(XB, WguT, rtok, rw, meta, ACT);
  moe_gemm2<<<4096, 256, 0, stream>>>(ACT, WdT, meta, ACT2);
  moe_combine<<<T_TOK, 256, 0, stream>>>(ACT2, ptok, pcnt, out);
}